// Round 1
// 484.963 us; speedup vs baseline: 1.0131x; 1.0131x over previous
//
#include <hip/hip_runtime.h>

// ---------------------------------------------------------------------------
// StructuralCausalModel: 3 layers x 32 vars sequential scan, BATCH=512.
// R9: R8 (delta-pc, step-top prefetch) +
//  (a) PA weights resident in VGPRs across all 96 steps (64 VGPR; removes the
//      16 b128 global loads/step that stage A had to drain vmcnt for),
//  (b) LDS strides Xs/X2 264->272, Hs 136->144 ushorts (row stride = 8 dwords
//      mod 32 -> uniform 2-way banks on the b128 A-frag reads, was 4-way),
//  (c) MFMA accumulators split into short independent chains (A: 4x4-chain,
//      B: 4x2, C: 2x2, D: 4x2) to halve dependent-MFMA latency.
// VGPR must stay <= 256 (8 waves/CU) with zero scratch.
// ---------------------------------------------------------------------------

typedef __bf16 bf16x8 __attribute__((ext_vector_type(8)));
typedef float  f32x4  __attribute__((ext_vector_type(4)));

#define N_VARS 32
#define BTILE 4
#define NBLK 128

// ws element offsets (bf16 region starts at byte 4096; adjT f32 at byte 0)
#define ELOFF_PA 0
#define ELOFF_W1 65536
#define ELOFF_W2 1114112
#define ELOFF_W3 1638400
// total bf16 el = 2686976 -> ws bytes = 4096 + 5373952

// LDS row strides (ushorts). 272*2B = 544B = 136 dw == 8 (mod 32) -> 2-way.
#define XSTR 272
#define HSTR 144

__device__ __forceinline__ unsigned short f2b(float f) {
    unsigned u = __float_as_uint(f);
    u += 0x7FFFu + ((u >> 16) & 1u);
    return (unsigned short)(u >> 16);
}

// lgkm-only barrier: LDS ordering enforced, global loads stay in flight.
__device__ __forceinline__ void bar_lds() {
    asm volatile("s_waitcnt lgkmcnt(0)\n\ts_barrier" ::: "memory");
}

// erf via Abramowitz-Stegun 7.1.25, 3 terms (|err| <= 2.5e-5)
__device__ __forceinline__ float gelu_e(float x) {
    float z  = x * 0.7071067811865476f;
    float az = fabsf(z);
    float t  = __builtin_amdgcn_rcpf(1.0f + 0.47047f * az);
    float p  = t * (0.3480242f + t * (-0.0958798f + t * 0.7478556f));
    float e  = 1.0f - p * __expf(-z * z);
    float er = (z < 0.0f) ? -e : e;
    return 0.5f * x * (1.0f + er);
}

// ---------------------------------------------------------------------------
// Prep (1545 blocks x 256): [0,520) weight swizzle via LDS tile (coalesced);
// 520 adjacency; [521,1545) noise encoder NE -> d_out (16 rows/block).
// B-frag (16x16x32): lane l, elem j -> k = ks*32+(l>>4)*8+j, n = nt*16+(l&15)
// ---------------------------------------------------------------------------
__global__ void prep_all(const float* __restrict__ paW, const float* __restrict__ mW1,
                         const float* __restrict__ mW2, const float* __restrict__ mW3,
                         const float* __restrict__ edge, unsigned short* __restrict__ wsb,
                         float* __restrict__ adjT,
                         const float* __restrict__ noise, const float* __restrict__ neW,
                         const float* __restrict__ neb, float* __restrict__ outp) {
    __shared__ unsigned short tile[32 * 256];
    const int c = blockIdx.x, tid = threadIdx.x;
    if (c < 520) {
        const float* src; unsigned short* dst; int N, KS, ks;
        if (c < 8)        { src = paW;                     dst = wsb + ELOFF_PA;             N = 256; KS = 8; ks = c; }
        else if (c < 264) { int v = (c - 8) >> 3;   ks = (c - 8) & 7;
                            src = mW1 + v * 32768;         dst = wsb + ELOFF_W1 + v * 32768; N = 128; KS = 8; }
        else if (c < 392) { int v = (c - 264) >> 2; ks = (c - 264) & 3;
                            src = mW2 + v * 16384;         dst = wsb + ELOFF_W2 + v * 16384; N = 128; KS = 4; }
        else              { int v = (c - 392) >> 2; ks = (c - 392) & 3;
                            src = mW3 + v * 32768;         dst = wsb + ELOFF_W3 + v * 32768; N = 256; KS = 4; }
        const int kb = ks * 32, nsh = (N == 256) ? 8 : 7;
        for (int t = tid; t < 32 * N; t += 256) {
            int r = t >> nsh, col = t & (N - 1);
            tile[r * N + col] = f2b(src[(kb + r) * N + col]);   // coalesced in col
        }
        __syncthreads();
        const int nout = (N >> 4) * 64;
        for (int o = tid; o < nout; o += 256) {
            int nt = o >> 6, lane = o & 63;
            int n = nt * 16 + (lane & 15), k0 = (lane >> 4) << 3;
            unsigned e[8];
            #pragma unroll
            for (int j = 0; j < 8; j++) e[j] = tile[(k0 + j) * N + n];
            uint4 pk;
            pk.x = e[0] | (e[1] << 16); pk.y = e[2] | (e[3] << 16);
            pk.z = e[4] | (e[5] << 16); pk.w = e[6] | (e[7] << 16);
            *(uint4*)(dst + ((nt * KS + ks) * 64 + lane) * 8) = pk;   // coalesced
        }
    } else if (c == 520) {
        for (int t = tid; t < 1024; t += 256) {
            int v = t >> 5, ci = t & 31;
            float x = edge[t];
            float m = (v == ci) ? 0.0f : x;   // diag logit masked -> adj diag = 0.5
            adjT[ci * 32 + v] = __builtin_amdgcn_rcpf(1.0f + __expf(-2.0f * m));
        }
    } else {
        int sb = c - 521;                     // 1024 sub-blocks: 32 vars x 32 groups
        int i = sb >> 5, g = sb & 31, d = tid;
        float w[64];
        #pragma unroll
        for (int k = 0; k < 64; k++) w[k] = neW[(i * 64 + k) * 256 + d];
        float bias = neb[i * 256 + d];
        for (int bb = 0; bb < 16; bb++) {
            int b = g * 16 + bb;
            const float* nr = noise + (b * 32 + i) * 64;
            float a0 = bias, a1 = 0.f, a2 = 0.f, a3 = 0.f;
            #pragma unroll
            for (int k = 0; k < 16; k++) {      // 4 independent fma chains
                a0 += nr[4 * k + 0] * w[4 * k + 0];
                a1 += nr[4 * k + 1] * w[4 * k + 1];
                a2 += nr[4 * k + 2] * w[4 * k + 2];
                a3 += nr[4 * k + 3] * w[4 * k + 3];
            }
            outp[(b * 32 + i) * 256 + d] = gelu_e((a0 + a1) + (a2 + a3));
        }
    }
}

#define MFMA16(a, b, c) __builtin_amdgcn_mfma_f32_16x16x32_bf16(a, b, c, 0, 0, 0)

// ---------------------------------------------------------------------------
// Main: 128 blocks x 512 threads (LDS 70.5 KB -> 1-2 blocks/CU; VGPR < 256).
// PA frags resident in regs. Per step: [top prefetch of per-var W1/W2/W3]
// A:pa  B:W1+pc(v<16)  C:W2+pc(v>=16)  D:W3->vals  E: pc delta fixup -> Xs.
// lgkm-only barriers (5/step).
// ---------------------------------------------------------------------------
__global__ __launch_bounds__(512) void
scm_main(const float* __restrict__ emb, const float* __restrict__ pab,
         const float* __restrict__ mb1, const float* __restrict__ mb2,
         const float* __restrict__ mb3, const float* __restrict__ adjT,
         const __bf16* __restrict__ wsbf, float* __restrict__ outp) {
    __shared__ unsigned short valsS[32 * 1024];   // [var][b<4][256 d]  64 KB
    __shared__ unsigned short Xs[4 * XSTR];
    __shared__ unsigned short X2[4 * XSTR];
    __shared__ unsigned short Hs1[4 * HSTR];
    __shared__ unsigned short Hs2[4 * HSTR];

    const int tid = threadIdx.x, blk = blockIdx.x;

    {   // zero vals
        uint4 z; z.x = z.y = z.z = z.w = 0;
        for (int k = tid; k < 4096; k += 512) ((uint4*)valsS)[k] = z;
    }

    const int wid = tid >> 6, lane = tid & 63, l15 = lane & 15, q = lane >> 4;
    const int l3 = l15 & 3;                 // A-frag row (BTILE=4; rows alias)
    const int nW = wid * 16 + l15;
    const int n0 = nW, n1 = nW + 128;
    // pc mapping: thread t -> row rE = t>>7, col pair cE = t&127 (cols 2*cE,2*cE+1)
    const int rE = tid >> 7, cE = tid & 127;

    const float pb0 = pab[n0], pb1 = pab[n1];

    // ---- PA fragments: load ONCE, resident in 64 VGPRs for all 96 steps ----
    bf16x8 paf0[8], paf1[8];
    #pragma unroll
    for (int ks = 0; ks < 8; ks++) {
        paf0[ks] = *(const bf16x8*)(wsbf + ELOFF_PA + ((wid * 8 + ks) * 64 + lane) * 8);
        paf1[ks] = *(const bf16x8*)(wsbf + ELOFF_PA + (((wid + 8) * 8 + ks) * 64 + lane) * 8);
    }

    // seed Xs for step 0: vals = 0 -> pc = 0 -> X = emb_0
    {
        float2 e0 = *(const float2*)(emb + cE * 2);
        *(unsigned*)(Xs + rE * XSTR + cE * 2) =
            (unsigned)f2b(e0.x) | ((unsigned)f2b(e0.y) << 16);
    }
    bar_lds();

    for (int s = 0; s < 3 * N_VARS; s++) {
        const int i = s & 31, ni = (s + 1) & 31;
        const bool last = s >= 64;
        const float* __restrict__ an = adjT + ni * 32;     // wave-uniform s_load

        // ---- step-top prefetch: all per-var step-i globals ----
        float bi1 = mb1[i * 128 + nW];
        float bi2 = mb2[i * 128 + nW];
        float b3a = mb3[i * 256 + n0];
        float b3b = mb3[i * 256 + n1];
        bf16x8 w1f[8];
        #pragma unroll
        for (int ks = 0; ks < 8; ks++)
            w1f[ks] = *(const bf16x8*)(wsbf + ELOFF_W1 + (size_t)i * 32768 +
                                       ((wid * 8 + ks) * 64 + lane) * 8);
        bf16x8 w2f[4], w3f0[4], w3f1[4];
        #pragma unroll
        for (int ks = 0; ks < 4; ks++) {
            w2f[ks]  = *(const bf16x8*)(wsbf + ELOFF_W2 + (size_t)i * 16384 +
                                        ((wid * 4 + ks) * 64 + lane) * 8);
            w3f0[ks] = *(const bf16x8*)(wsbf + ELOFF_W3 + (size_t)i * 32768 +
                                        ((wid * 4 + ks) * 64 + lane) * 8);
            w3f1[ks] = *(const bf16x8*)(wsbf + ELOFF_W3 + (size_t)i * 32768 +
                                        (((wid + 8) * 4 + ks) * 64 + lane) * 8);
        }
        float ne0[4], ne1[4];
        #pragma unroll
        for (int r = 0; r < 4; r++) { ne0[r] = 0.f; ne1[r] = 0.f; }
        if (q == 0) {
            #pragma unroll
            for (int r = 0; r < 4; r++) {
                size_t ob = ((size_t)(blk * BTILE + r) * 32 + i) * 256;
                ne0[r] = outp[ob + n0];
                ne1[r] = outp[ob + n1];
            }
        }

        // ==== A: pa = gelu(X @ pa_W + pa_b) ====  (regs + LDS only; no vmcnt)
        {
            f32x4 a0e = {0, 0, 0, 0}, a0o = {0, 0, 0, 0};
            f32x4 a1e = {0, 0, 0, 0}, a1o = {0, 0, 0, 0};
            #pragma unroll
            for (int ks = 0; ks < 8; ks += 2) {
                bf16x8 af0 = *(const bf16x8*)(Xs + l3 * XSTR + ks * 32 + q * 8);
                bf16x8 af1 = *(const bf16x8*)(Xs + l3 * XSTR + (ks + 1) * 32 + q * 8);
                a0e = MFMA16(af0, paf0[ks], a0e);
                a1e = MFMA16(af0, paf1[ks], a1e);
                a0o = MFMA16(af1, paf0[ks + 1], a0o);
                a1o = MFMA16(af1, paf1[ks + 1], a1o);
            }
            if (q == 0) {
                f32x4 acc0 = a0e + a0o, acc1 = a1e + a1o;
                #pragma unroll
                for (int r = 0; r < 4; r++) {
                    X2[r * XSTR + n0] = f2b(gelu_e(acc0[r] + pb0));
                    X2[r * XSTR + n1] = f2b(gelu_e(acc1[r] + pb1));
                }
            }
        }
        bar_lds();

        // ==== B: W1 GEMM; partial-pc v=0..15 (pre-update vals); old_i snap ====
        float p0 = 0.f, p1 = 0.f, of0, of1;
        {
            f32x4 aa = {0, 0, 0, 0}, ab = {0, 0, 0, 0};
            f32x4 ac = {0, 0, 0, 0}, ad = {0, 0, 0, 0};
            #pragma unroll
            for (int ks = 0; ks < 8; ks += 4) {
                bf16x8 af0 = *(const bf16x8*)(X2 + l3 * XSTR + ks * 32 + q * 8);
                bf16x8 af1 = *(const bf16x8*)(X2 + l3 * XSTR + (ks + 1) * 32 + q * 8);
                bf16x8 af2 = *(const bf16x8*)(X2 + l3 * XSTR + (ks + 2) * 32 + q * 8);
                bf16x8 af3 = *(const bf16x8*)(X2 + l3 * XSTR + (ks + 3) * 32 + q * 8);
                aa = MFMA16(af0, w1f[ks], aa);
                ab = MFMA16(af1, w1f[ks + 1], ab);
                ac = MFMA16(af2, w1f[ks + 2], ac);
                ad = MFMA16(af3, w1f[ks + 3], ad);
            }
            const unsigned short* vp = valsS + rE * 256 + cE * 2;
            #pragma unroll
            for (int v = 0; v < 16; v++) {
                unsigned u = *(const unsigned*)(vp + v * 1024);
                float sc = an[v];
                p0 += sc * __uint_as_float(u << 16);
                p1 += sc * __uint_as_float(u & 0xFFFF0000u);
            }
            {
                unsigned uo = *(const unsigned*)(valsS + i * 1024 + rE * 256 + cE * 2);
                of0 = __uint_as_float(uo << 16);
                of1 = __uint_as_float(uo & 0xFFFF0000u);
            }
            if (q == 0) {
                f32x4 acc = (aa + ab) + (ac + ad);
                #pragma unroll
                for (int r = 0; r < 4; r++)
                    Hs1[r * HSTR + nW] = f2b(gelu_e(acc[r] + bi1));
            }
        }
        bar_lds();

        // ==== C: W2 GEMM; partial-pc v=16..31; emb(ni) load ====
        float2 e2n = *(const float2*)(emb + ni * 256 + cE * 2);
        {
            f32x4 ca = {0, 0, 0, 0}, cb = {0, 0, 0, 0};
            #pragma unroll
            for (int ks = 0; ks < 4; ks += 2) {
                bf16x8 af0 = *(const bf16x8*)(Hs1 + l3 * HSTR + ks * 32 + q * 8);
                bf16x8 af1 = *(const bf16x8*)(Hs1 + l3 * HSTR + (ks + 1) * 32 + q * 8);
                ca = MFMA16(af0, w2f[ks], ca);
                cb = MFMA16(af1, w2f[ks + 1], cb);
            }
            const unsigned short* vp = valsS + rE * 256 + cE * 2;
            #pragma unroll
            for (int v = 16; v < 32; v++) {
                unsigned u = *(const unsigned*)(vp + v * 1024);
                float sc = an[v];
                p0 += sc * __uint_as_float(u << 16);
                p1 += sc * __uint_as_float(u & 0xFFFF0000u);
            }
            if (q == 0) {
                f32x4 acc = ca + cb;
                #pragma unroll
                for (int r = 0; r < 4; r++)
                    Hs2[r * HSTR + nW] = f2b(gelu_e(acc[r] + bi2));
            }
        }
        bar_lds();

        // ==== D: W3 GEMM + b3 + NE -> vals[i] (and outp at layer 2) ====
        {
            f32x4 c0a = {0, 0, 0, 0}, c0b = {0, 0, 0, 0};
            f32x4 c1a = {0, 0, 0, 0}, c1b = {0, 0, 0, 0};
            #pragma unroll
            for (int ks = 0; ks < 4; ks += 2) {
                bf16x8 af0 = *(const bf16x8*)(Hs2 + l3 * HSTR + ks * 32 + q * 8);
                bf16x8 af1 = *(const bf16x8*)(Hs2 + l3 * HSTR + (ks + 1) * 32 + q * 8);
                c0a = MFMA16(af0, w3f0[ks], c0a);
                c1a = MFMA16(af0, w3f1[ks], c1a);
                c0b = MFMA16(af1, w3f0[ks + 1], c0b);
                c1b = MFMA16(af1, w3f1[ks + 1], c1b);
            }
            if (q == 0) {
                f32x4 acc0 = c0a + c0b, acc1 = c1a + c1b;
                #pragma unroll
                for (int r = 0; r < 4; r++) {
                    float v0 = acc0[r] + b3a + ne0[r];
                    float v1 = acc1[r] + b3b + ne1[r];
                    valsS[i * 1024 + r * 256 + n0] = f2b(v0);
                    valsS[i * 1024 + r * 256 + n1] = f2b(v1);
                    if (last) {
                        size_t ob = ((size_t)(blk * BTILE + r) * 32 + i) * 256;
                        outp[ob + n0] = v0;
                        outp[ob + n1] = v1;
                    }
                }
            }
        }
        bar_lds();

        // ==== E: pc delta fixup -> Xs for step ni ====
        {
            unsigned un = *(const unsigned*)(valsS + i * 1024 + rE * 256 + cE * 2);
            float av = an[i];                        // a[i, ni]
            float x0 = p0 + av * (__uint_as_float(un << 16)          - of0) + e2n.x;
            float x1 = p1 + av * (__uint_as_float(un & 0xFFFF0000u)  - of1) + e2n.y;
            *(unsigned*)(Xs + rE * XSTR + cE * 2) =
                (unsigned)f2b(x0) | ((unsigned)f2b(x1) << 16);
        }
        bar_lds();
    }
}

extern "C" void kernel_launch(void* const* d_in, const int* in_sizes, int n_in,
                              void* d_out, int out_size, void* d_ws, size_t ws_size,
                              hipStream_t stream) {
    (void)in_sizes; (void)n_in; (void)out_size; (void)ws_size;
    const float* noise = (const float*)d_in[0];
    const float* edge  = (const float*)d_in[1];
    const float* emb   = (const float*)d_in[2];
    const float* paW   = (const float*)d_in[3];
    const float* pab   = (const float*)d_in[4];
    const float* mW1   = (const float*)d_in[5];
    const float* mb1   = (const float*)d_in[6];
    const float* mW2   = (const float*)d_in[7];
    const float* mb2   = (const float*)d_in[8];
    const float* mW3   = (const float*)d_in[9];
    const float* mb3   = (const float*)d_in[10];
    const float* neW   = (const float*)d_in[11];
    const float* neb   = (const float*)d_in[12];
    float* outp = (float*)d_out;

    float* adjT = (float*)d_ws;
    unsigned short* wsb = (unsigned short*)((char*)d_ws + 4096);

    prep_all<<<1545, 256, 0, stream>>>(paW, mW1, mW2, mW3, edge, wsb, adjT,
                                       noise, neW, neb, outp);
    scm_main<<<NBLK, 512, 0, stream>>>(emb, pab, mb1, mb2, mb3, adjT,
                                       (const __bf16*)wsb, outp);
}

// Round 2
// 387.661 us; speedup vs baseline: 1.2673x; 1.2510x over previous
//
#include <hip/hip_runtime.h>

// ---------------------------------------------------------------------------
// StructuralCausalModel: 3 layers x 32 vars sequential scan, BATCH=512.
// R10: R9 (PA-resident, conflict-free strides, short MFMA chains) +
// row-redistributed epilogues: MFMA C-layout duplicates rows across the 4
// lane-quads (A rows alias l15&3), so lane (q,c) extracts acc element q and
// handles ONLY row q. gelu work per wave drops 8->2 (A,D) and 4->1 (B,C);
// NE loads / valsS / outp writes shrink 4x; all 64 lanes active. Values are
// bit-identical to R9 (same math, different lanes).
// ---------------------------------------------------------------------------

typedef __bf16 bf16x8 __attribute__((ext_vector_type(8)));
typedef float  f32x4  __attribute__((ext_vector_type(4)));

#define N_VARS 32
#define BTILE 4
#define NBLK 128

// ws element offsets (bf16 region starts at byte 4096; adjT f32 at byte 0)
#define ELOFF_PA 0
#define ELOFF_W1 65536
#define ELOFF_W2 1114112
#define ELOFF_W3 1638400
// total bf16 el = 2686976 -> ws bytes = 4096 + 5373952

// LDS row strides (ushorts). 272*2B = 136 dw == 8 (mod 32) -> 2-way banks.
#define XSTR 272
#define HSTR 144

__device__ __forceinline__ unsigned short f2b(float f) {
    unsigned u = __float_as_uint(f);
    u += 0x7FFFu + ((u >> 16) & 1u);
    return (unsigned short)(u >> 16);
}

// lgkm-only barrier: LDS ordering enforced, global loads stay in flight.
__device__ __forceinline__ void bar_lds() {
    asm volatile("s_waitcnt lgkmcnt(0)\n\ts_barrier" ::: "memory");
}

// erf via Abramowitz-Stegun 7.1.25, 3 terms (|err| <= 2.5e-5)
__device__ __forceinline__ float gelu_e(float x) {
    float z  = x * 0.7071067811865476f;
    float az = fabsf(z);
    float t  = __builtin_amdgcn_rcpf(1.0f + 0.47047f * az);
    float p  = t * (0.3480242f + t * (-0.0958798f + t * 0.7478556f));
    float e  = 1.0f - p * __expf(-z * z);
    float er = (z < 0.0f) ? -e : e;
    return 0.5f * x * (1.0f + er);
}

// Extract element q (q = lane>>4, runtime) via compile-time-indexed selects.
// No runtime vector indexing -> no scratch (rule: dyn-idx ext_vector spills).
__device__ __forceinline__ float pickq(f32x4 v, int q) {
    float lo = (q & 1) ? v[1] : v[0];
    float hi = (q & 1) ? v[3] : v[2];
    return (q & 2) ? hi : lo;
}

// ---------------------------------------------------------------------------
// Prep (1545 blocks x 256): [0,520) weight swizzle via LDS tile (coalesced);
// 520 adjacency; [521,1545) noise encoder NE -> d_out (16 rows/block).
// B-frag (16x16x32): lane l, elem j -> k = ks*32+(l>>4)*8+j, n = nt*16+(l&15)
// ---------------------------------------------------------------------------
__global__ void prep_all(const float* __restrict__ paW, const float* __restrict__ mW1,
                         const float* __restrict__ mW2, const float* __restrict__ mW3,
                         const float* __restrict__ edge, unsigned short* __restrict__ wsb,
                         float* __restrict__ adjT,
                         const float* __restrict__ noise, const float* __restrict__ neW,
                         const float* __restrict__ neb, float* __restrict__ outp) {
    __shared__ unsigned short tile[32 * 256];
    const int c = blockIdx.x, tid = threadIdx.x;
    if (c < 520) {
        const float* src; unsigned short* dst; int N, KS, ks;
        if (c < 8)        { src = paW;                     dst = wsb + ELOFF_PA;             N = 256; KS = 8; ks = c; }
        else if (c < 264) { int v = (c - 8) >> 3;   ks = (c - 8) & 7;
                            src = mW1 + v * 32768;         dst = wsb + ELOFF_W1 + v * 32768; N = 128; KS = 8; }
        else if (c < 392) { int v = (c - 264) >> 2; ks = (c - 264) & 3;
                            src = mW2 + v * 16384;         dst = wsb + ELOFF_W2 + v * 16384; N = 128; KS = 4; }
        else              { int v = (c - 392) >> 2; ks = (c - 392) & 3;
                            src = mW3 + v * 32768;         dst = wsb + ELOFF_W3 + v * 32768; N = 256; KS = 4; }
        const int kb = ks * 32, nsh = (N == 256) ? 8 : 7;
        for (int t = tid; t < 32 * N; t += 256) {
            int r = t >> nsh, col = t & (N - 1);
            tile[r * N + col] = f2b(src[(kb + r) * N + col]);   // coalesced in col
        }
        __syncthreads();
        const int nout = (N >> 4) * 64;
        for (int o = tid; o < nout; o += 256) {
            int nt = o >> 6, lane = o & 63;
            int n = nt * 16 + (lane & 15), k0 = (lane >> 4) << 3;
            unsigned e[8];
            #pragma unroll
            for (int j = 0; j < 8; j++) e[j] = tile[(k0 + j) * N + n];
            uint4 pk;
            pk.x = e[0] | (e[1] << 16); pk.y = e[2] | (e[3] << 16);
            pk.z = e[4] | (e[5] << 16); pk.w = e[6] | (e[7] << 16);
            *(uint4*)(dst + ((nt * KS + ks) * 64 + lane) * 8) = pk;   // coalesced
        }
    } else if (c == 520) {
        for (int t = tid; t < 1024; t += 256) {
            int v = t >> 5, ci = t & 31;
            float x = edge[t];
            float m = (v == ci) ? 0.0f : x;   // diag logit masked -> adj diag = 0.5
            adjT[ci * 32 + v] = __builtin_amdgcn_rcpf(1.0f + __expf(-2.0f * m));
        }
    } else {
        int sb = c - 521;                     // 1024 sub-blocks: 32 vars x 32 groups
        int i = sb >> 5, g = sb & 31, d = tid;
        float w[64];
        #pragma unroll
        for (int k = 0; k < 64; k++) w[k] = neW[(i * 64 + k) * 256 + d];
        float bias = neb[i * 256 + d];
        for (int bb = 0; bb < 16; bb++) {
            int b = g * 16 + bb;
            const float* nr = noise + (b * 32 + i) * 64;
            float a0 = bias, a1 = 0.f, a2 = 0.f, a3 = 0.f;
            #pragma unroll
            for (int k = 0; k < 16; k++) {      // 4 independent fma chains
                a0 += nr[4 * k + 0] * w[4 * k + 0];
                a1 += nr[4 * k + 1] * w[4 * k + 1];
                a2 += nr[4 * k + 2] * w[4 * k + 2];
                a3 += nr[4 * k + 3] * w[4 * k + 3];
            }
            outp[(b * 32 + i) * 256 + d] = gelu_e((a0 + a1) + (a2 + a3));
        }
    }
}

#define MFMA16(a, b, c) __builtin_amdgcn_mfma_f32_16x16x32_bf16(a, b, c, 0, 0, 0)

// ---------------------------------------------------------------------------
// Main: 128 blocks x 512 threads (LDS 70.5 KB; VGPR ~110).
// PA frags resident in regs. Per step: [top prefetch of per-var W1/W2/W3]
// A:pa  B:W1+pc(v<16)  C:W2+pc(v>=16)  D:W3->vals  E: pc delta fixup -> Xs.
// lgkm-only barriers (5/step). Epilogues row-redistributed across lane-quads.
// ---------------------------------------------------------------------------
__global__ __launch_bounds__(512) void
scm_main(const float* __restrict__ emb, const float* __restrict__ pab,
         const float* __restrict__ mb1, const float* __restrict__ mb2,
         const float* __restrict__ mb3, const float* __restrict__ adjT,
         const __bf16* __restrict__ wsbf, float* __restrict__ outp) {
    __shared__ unsigned short valsS[32 * 1024];   // [var][b<4][256 d]  64 KB
    __shared__ unsigned short Xs[4 * XSTR];
    __shared__ unsigned short X2[4 * XSTR];
    __shared__ unsigned short Hs1[4 * HSTR];
    __shared__ unsigned short Hs2[4 * HSTR];

    const int tid = threadIdx.x, blk = blockIdx.x;

    {   // zero vals
        uint4 z; z.x = z.y = z.z = z.w = 0;
        for (int k = tid; k < 4096; k += 512) ((uint4*)valsS)[k] = z;
    }

    const int wid = tid >> 6, lane = tid & 63, l15 = lane & 15, q = lane >> 4;
    const int l3 = l15 & 3;                 // A-frag row (BTILE=4; rows alias)
    const int nW = wid * 16 + l15;
    const int n0 = nW, n1 = nW + 128;
    // pc mapping: thread t -> row rE = t>>7, col pair cE = t&127 (cols 2*cE,2*cE+1)
    const int rE = tid >> 7, cE = tid & 127;

    const float pb0 = pab[n0], pb1 = pab[n1];

    // ---- PA fragments: load ONCE, resident in 64 VGPRs for all 96 steps ----
    bf16x8 paf0[8], paf1[8];
    #pragma unroll
    for (int ks = 0; ks < 8; ks++) {
        paf0[ks] = *(const bf16x8*)(wsbf + ELOFF_PA + ((wid * 8 + ks) * 64 + lane) * 8);
        paf1[ks] = *(const bf16x8*)(wsbf + ELOFF_PA + (((wid + 8) * 8 + ks) * 64 + lane) * 8);
    }

    // seed Xs for step 0: vals = 0 -> pc = 0 -> X = emb_0
    {
        float2 e0 = *(const float2*)(emb + cE * 2);
        *(unsigned*)(Xs + rE * XSTR + cE * 2) =
            (unsigned)f2b(e0.x) | ((unsigned)f2b(e0.y) << 16);
    }
    bar_lds();

    for (int s = 0; s < 3 * N_VARS; s++) {
        const int i = s & 31, ni = (s + 1) & 31;
        const bool last = s >= 64;
        const float* __restrict__ an = adjT + ni * 32;     // wave-uniform s_load

        // ---- step-top prefetch: all per-var step-i globals ----
        float bi1 = mb1[i * 128 + nW];
        float bi2 = mb2[i * 128 + nW];
        float b3a = mb3[i * 256 + n0];
        float b3b = mb3[i * 256 + n1];
        bf16x8 w1f[8];
        #pragma unroll
        for (int ks = 0; ks < 8; ks++)
            w1f[ks] = *(const bf16x8*)(wsbf + ELOFF_W1 + (size_t)i * 32768 +
                                       ((wid * 8 + ks) * 64 + lane) * 8);
        bf16x8 w2f[4], w3f0[4], w3f1[4];
        #pragma unroll
        for (int ks = 0; ks < 4; ks++) {
            w2f[ks]  = *(const bf16x8*)(wsbf + ELOFF_W2 + (size_t)i * 16384 +
                                        ((wid * 4 + ks) * 64 + lane) * 8);
            w3f0[ks] = *(const bf16x8*)(wsbf + ELOFF_W3 + (size_t)i * 32768 +
                                        ((wid * 4 + ks) * 64 + lane) * 8);
            w3f1[ks] = *(const bf16x8*)(wsbf + ELOFF_W3 + (size_t)i * 32768 +
                                        (((wid + 8) * 4 + ks) * 64 + lane) * 8);
        }
        // NE contribution for (row q, cols n0/n1) — 2 full-wave coalesced loads
        const size_t obq = ((size_t)(blk * BTILE + q) * 32 + i) * 256;
        const float neq0 = outp[obq + n0];
        const float neq1 = outp[obq + n1];

        // ==== A: pa = gelu(X @ pa_W + pa_b) ====  (regs + LDS only; no vmcnt)
        {
            f32x4 a0e = {0, 0, 0, 0}, a0o = {0, 0, 0, 0};
            f32x4 a1e = {0, 0, 0, 0}, a1o = {0, 0, 0, 0};
            #pragma unroll
            for (int ks = 0; ks < 8; ks += 2) {
                bf16x8 af0 = *(const bf16x8*)(Xs + l3 * XSTR + ks * 32 + q * 8);
                bf16x8 af1 = *(const bf16x8*)(Xs + l3 * XSTR + (ks + 1) * 32 + q * 8);
                a0e = MFMA16(af0, paf0[ks], a0e);
                a1e = MFMA16(af0, paf1[ks], a1e);
                a0o = MFMA16(af1, paf0[ks + 1], a0o);
                a1o = MFMA16(af1, paf1[ks + 1], a1o);
            }
            // lane (q,c) handles row q only (rows duplicated across quads)
            float s0 = pickq(a0e, q) + pickq(a0o, q) + pb0;
            float s1 = pickq(a1e, q) + pickq(a1o, q) + pb1;
            X2[q * XSTR + n0] = f2b(gelu_e(s0));
            X2[q * XSTR + n1] = f2b(gelu_e(s1));
        }
        bar_lds();

        // ==== B: W1 GEMM; partial-pc v=0..15 (pre-update vals); old_i snap ====
        float p0 = 0.f, p1 = 0.f, of0, of1;
        {
            f32x4 aa = {0, 0, 0, 0}, ab = {0, 0, 0, 0};
            f32x4 ac = {0, 0, 0, 0}, ad = {0, 0, 0, 0};
            #pragma unroll
            for (int ks = 0; ks < 8; ks += 4) {
                bf16x8 af0 = *(const bf16x8*)(X2 + l3 * XSTR + ks * 32 + q * 8);
                bf16x8 af1 = *(const bf16x8*)(X2 + l3 * XSTR + (ks + 1) * 32 + q * 8);
                bf16x8 af2 = *(const bf16x8*)(X2 + l3 * XSTR + (ks + 2) * 32 + q * 8);
                bf16x8 af3 = *(const bf16x8*)(X2 + l3 * XSTR + (ks + 3) * 32 + q * 8);
                aa = MFMA16(af0, w1f[ks], aa);
                ab = MFMA16(af1, w1f[ks + 1], ab);
                ac = MFMA16(af2, w1f[ks + 2], ac);
                ad = MFMA16(af3, w1f[ks + 3], ad);
            }
            const unsigned short* vp = valsS + rE * 256 + cE * 2;
            #pragma unroll
            for (int v = 0; v < 16; v++) {
                unsigned u = *(const unsigned*)(vp + v * 1024);
                float sc = an[v];
                p0 += sc * __uint_as_float(u << 16);
                p1 += sc * __uint_as_float(u & 0xFFFF0000u);
            }
            {
                unsigned uo = *(const unsigned*)(valsS + i * 1024 + rE * 256 + cE * 2);
                of0 = __uint_as_float(uo << 16);
                of1 = __uint_as_float(uo & 0xFFFF0000u);
            }
            float sb = (pickq(aa, q) + pickq(ab, q)) +
                       (pickq(ac, q) + pickq(ad, q)) + bi1;
            Hs1[q * HSTR + nW] = f2b(gelu_e(sb));
        }
        bar_lds();

        // ==== C: W2 GEMM; partial-pc v=16..31; emb(ni) load ====
        float2 e2n = *(const float2*)(emb + ni * 256 + cE * 2);
        {
            f32x4 ca = {0, 0, 0, 0}, cb = {0, 0, 0, 0};
            #pragma unroll
            for (int ks = 0; ks < 4; ks += 2) {
                bf16x8 af0 = *(const bf16x8*)(Hs1 + l3 * HSTR + ks * 32 + q * 8);
                bf16x8 af1 = *(const bf16x8*)(Hs1 + l3 * HSTR + (ks + 1) * 32 + q * 8);
                ca = MFMA16(af0, w2f[ks], ca);
                cb = MFMA16(af1, w2f[ks + 1], cb);
            }
            const unsigned short* vp = valsS + rE * 256 + cE * 2;
            #pragma unroll
            for (int v = 16; v < 32; v++) {
                unsigned u = *(const unsigned*)(vp + v * 1024);
                float sc = an[v];
                p0 += sc * __uint_as_float(u << 16);
                p1 += sc * __uint_as_float(u & 0xFFFF0000u);
            }
            float scv = pickq(ca, q) + pickq(cb, q) + bi2;
            Hs2[q * HSTR + nW] = f2b(gelu_e(scv));
        }
        bar_lds();

        // ==== D: W3 GEMM + b3 + NE -> vals[i] (and outp at layer 2) ====
        {
            f32x4 c0a = {0, 0, 0, 0}, c0b = {0, 0, 0, 0};
            f32x4 c1a = {0, 0, 0, 0}, c1b = {0, 0, 0, 0};
            #pragma unroll
            for (int ks = 0; ks < 4; ks += 2) {
                bf16x8 af0 = *(const bf16x8*)(Hs2 + l3 * HSTR + ks * 32 + q * 8);
                bf16x8 af1 = *(const bf16x8*)(Hs2 + l3 * HSTR + (ks + 1) * 32 + q * 8);
                c0a = MFMA16(af0, w3f0[ks], c0a);
                c1a = MFMA16(af0, w3f1[ks], c1a);
                c0b = MFMA16(af1, w3f0[ks + 1], c0b);
                c1b = MFMA16(af1, w3f1[ks + 1], c1b);
            }
            float v0 = pickq(c0a, q) + pickq(c0b, q) + b3a + neq0;
            float v1 = pickq(c1a, q) + pickq(c1b, q) + b3b + neq1;
            valsS[i * 1024 + q * 256 + n0] = f2b(v0);
            valsS[i * 1024 + q * 256 + n1] = f2b(v1);
            if (last) {
                outp[obq + n0] = v0;
                outp[obq + n1] = v1;
            }
        }
        bar_lds();

        // ==== E: pc delta fixup -> Xs for step ni ====
        {
            unsigned un = *(const unsigned*)(valsS + i * 1024 + rE * 256 + cE * 2);
            float av = an[i];                        // a[i, ni]
            float x0 = p0 + av * (__uint_as_float(un << 16)          - of0) + e2n.x;
            float x1 = p1 + av * (__uint_as_float(un & 0xFFFF0000u)  - of1) + e2n.y;
            *(unsigned*)(Xs + rE * XSTR + cE * 2) =
                (unsigned)f2b(x0) | ((unsigned)f2b(x1) << 16);
        }
        bar_lds();
    }
}

extern "C" void kernel_launch(void* const* d_in, const int* in_sizes, int n_in,
                              void* d_out, int out_size, void* d_ws, size_t ws_size,
                              hipStream_t stream) {
    (void)in_sizes; (void)n_in; (void)out_size; (void)ws_size;
    const float* noise = (const float*)d_in[0];
    const float* edge  = (const float*)d_in[1];
    const float* emb   = (const float*)d_in[2];
    const float* paW   = (const float*)d_in[3];
    const float* pab   = (const float*)d_in[4];
    const float* mW1   = (const float*)d_in[5];
    const float* mb1   = (const float*)d_in[6];
    const float* mW2   = (const float*)d_in[7];
    const float* mb2   = (const float*)d_in[8];
    const float* mW3   = (const float*)d_in[9];
    const float* mb3   = (const float*)d_in[10];
    const float* neW   = (const float*)d_in[11];
    const float* neb   = (const float*)d_in[12];
    float* outp = (float*)d_out;

    float* adjT = (float*)d_ws;
    unsigned short* wsb = (unsigned short*)((char*)d_ws + 4096);

    prep_all<<<1545, 256, 0, stream>>>(paW, mW1, mW2, mW3, edge, wsb, adjT,
                                       noise, neW, neb, outp);
    scm_main<<<NBLK, 512, 0, stream>>>(emb, pab, mb1, mb2, mb3, adjT,
                                       (const __bf16*)wsb, outp);
}

// Round 3
// 373.481 us; speedup vs baseline: 1.3154x; 1.0380x over previous
//
#include <hip/hip_runtime.h>

// ---------------------------------------------------------------------------
// StructuralCausalModel: 3 layers x 32 vars sequential scan, BATCH=512.
// R11: R10 (PA-resident, row-redistributed epilogues) +
//  (a) pc as MFMA: vals stored column-major valsT[(b*256+d)][v] (stride 40);
//      pc = one K=32 GEMM with A-rows = an (bf16 hi/lo pair for f32 accuracy,
//      2 chained MFMAs/tile). Deletes the 128-inst serial pc VALU loop and
//      its 32 ds_read_b32 per lane.
//  (b) pc ownership = GEMM epilogue ownership (lane (q,l15) owns rows q,
//      cols n0/n1) -> the delta fixup is lane-local at end of stage D;
//      stage E and its barrier are GONE: 4 barriers/step instead of 5.
//  (c) adjacency ws slot (4KB) repurposed: [ni][hi[32],lo[32]] bf16.
// LDS 88.6 KB (1 block/CU). VGPR target < 256, no scratch.
// ---------------------------------------------------------------------------

typedef __bf16 bf16x8 __attribute__((ext_vector_type(8)));
typedef float  f32x4  __attribute__((ext_vector_type(4)));

#define N_VARS 32
#define BTILE 4
#define NBLK 128

// ws element offsets (bf16 region starts at byte 4096; adjb bf16 at byte 0)
#define ELOFF_PA 0
#define ELOFF_W1 65536
#define ELOFF_W2 1114112
#define ELOFF_W3 1638400
// total bf16 el = 2686976 -> ws bytes = 4096 + 5373952 (unchanged)

// LDS row strides (ushorts). XSTR: 136 dw == 8 (mod 32) -> 2-way banks.
#define XSTR 272
#define HSTR 144
#define VSTR 40    // valsT col stride (80 B): frag reads 16B-aligned, ~2-4 way

__device__ __forceinline__ unsigned short f2b(float f) {
    unsigned u = __float_as_uint(f);
    u += 0x7FFFu + ((u >> 16) & 1u);
    return (unsigned short)(u >> 16);
}

__device__ __forceinline__ float b2f(unsigned short u) {
    return __uint_as_float(((unsigned)u) << 16);
}

// lgkm-only barrier: LDS ordering enforced, global loads stay in flight.
__device__ __forceinline__ void bar_lds() {
    asm volatile("s_waitcnt lgkmcnt(0)\n\ts_barrier" ::: "memory");
}

// erf via Abramowitz-Stegun 7.1.25, 3 terms (|err| <= 2.5e-5)
__device__ __forceinline__ float gelu_e(float x) {
    float z  = x * 0.7071067811865476f;
    float az = fabsf(z);
    float t  = __builtin_amdgcn_rcpf(1.0f + 0.47047f * az);
    float p  = t * (0.3480242f + t * (-0.0958798f + t * 0.7478556f));
    float e  = 1.0f - p * __expf(-z * z);
    float er = (z < 0.0f) ? -e : e;
    return 0.5f * x * (1.0f + er);
}

// Extract element q (q = lane>>4, runtime) via compile-time-indexed selects.
__device__ __forceinline__ float pickq(f32x4 v, int q) {
    float lo = (q & 1) ? v[1] : v[0];
    float hi = (q & 1) ? v[3] : v[2];
    return (q & 2) ? hi : lo;
}
__device__ __forceinline__ float pick4(float x0, float x1, float x2, float x3, int q) {
    float lo = (q & 1) ? x1 : x0;
    float hi = (q & 1) ? x3 : x2;
    return (q & 2) ? hi : lo;
}

// ---------------------------------------------------------------------------
// Prep (1545 blocks x 256): [0,520) weight swizzle via LDS tile (coalesced);
// 520 adjacency (bf16 hi/lo); [521,1545) noise encoder NE -> d_out.
// B-frag (16x16x32): lane l, elem j -> k = ks*32+(l>>4)*8+j, n = nt*16+(l&15)
// ---------------------------------------------------------------------------
__global__ void prep_all(const float* __restrict__ paW, const float* __restrict__ mW1,
                         const float* __restrict__ mW2, const float* __restrict__ mW3,
                         const float* __restrict__ edge, unsigned short* __restrict__ wsb,
                         unsigned short* __restrict__ adjb,
                         const float* __restrict__ noise, const float* __restrict__ neW,
                         const float* __restrict__ neb, float* __restrict__ outp) {
    __shared__ unsigned short tile[32 * 256];
    const int c = blockIdx.x, tid = threadIdx.x;
    if (c < 520) {
        const float* src; unsigned short* dst; int N, KS, ks;
        if (c < 8)        { src = paW;                     dst = wsb + ELOFF_PA;             N = 256; KS = 8; ks = c; }
        else if (c < 264) { int v = (c - 8) >> 3;   ks = (c - 8) & 7;
                            src = mW1 + v * 32768;         dst = wsb + ELOFF_W1 + v * 32768; N = 128; KS = 8; }
        else if (c < 392) { int v = (c - 264) >> 2; ks = (c - 264) & 3;
                            src = mW2 + v * 16384;         dst = wsb + ELOFF_W2 + v * 16384; N = 128; KS = 4; }
        else              { int v = (c - 392) >> 2; ks = (c - 392) & 3;
                            src = mW3 + v * 32768;         dst = wsb + ELOFF_W3 + v * 32768; N = 256; KS = 4; }
        const int kb = ks * 32, nsh = (N == 256) ? 8 : 7;
        for (int t = tid; t < 32 * N; t += 256) {
            int r = t >> nsh, col = t & (N - 1);
            tile[r * N + col] = f2b(src[(kb + r) * N + col]);   // coalesced in col
        }
        __syncthreads();
        const int nout = (N >> 4) * 64;
        for (int o = tid; o < nout; o += 256) {
            int nt = o >> 6, lane = o & 63;
            int n = nt * 16 + (lane & 15), k0 = (lane >> 4) << 3;
            unsigned e[8];
            #pragma unroll
            for (int j = 0; j < 8; j++) e[j] = tile[(k0 + j) * N + n];
            uint4 pk;
            pk.x = e[0] | (e[1] << 16); pk.y = e[2] | (e[3] << 16);
            pk.z = e[4] | (e[5] << 16); pk.w = e[6] | (e[7] << 16);
            *(uint4*)(dst + ((nt * KS + ks) * 64 + lane) * 8) = pk;   // coalesced
        }
    } else if (c == 520) {
        for (int t = tid; t < 1024; t += 256) {
            int v = t >> 5, ci = t & 31;
            float x = edge[t];
            float m = (v == ci) ? 0.0f : x;   // diag logit masked -> adj diag = 0.5
            float a = __builtin_amdgcn_rcpf(1.0f + __expf(-2.0f * m));
            unsigned short hi = f2b(a);
            float rem = a - b2f(hi);
            adjb[ci * 64 + v]      = hi;        // row ci: parents-of-ci weights
            adjb[ci * 64 + 32 + v] = f2b(rem);  // low part (an ~ 16-bit mantissa)
        }
    } else {
        int sb = c - 521;                     // 1024 sub-blocks: 32 vars x 32 groups
        int i = sb >> 5, g = sb & 31, d = tid;
        float w[64];
        #pragma unroll
        for (int k = 0; k < 64; k++) w[k] = neW[(i * 64 + k) * 256 + d];
        float bias = neb[i * 256 + d];
        for (int bb = 0; bb < 16; bb++) {
            int b = g * 16 + bb;
            const float* nr = noise + (b * 32 + i) * 64;
            float a0 = bias, a1 = 0.f, a2 = 0.f, a3 = 0.f;
            #pragma unroll
            for (int k = 0; k < 16; k++) {      // 4 independent fma chains
                a0 += nr[4 * k + 0] * w[4 * k + 0];
                a1 += nr[4 * k + 1] * w[4 * k + 1];
                a2 += nr[4 * k + 2] * w[4 * k + 2];
                a3 += nr[4 * k + 3] * w[4 * k + 3];
            }
            outp[(b * 32 + i) * 256 + d] = gelu_e((a0 + a1) + (a2 + a3));
        }
    }
}

#define MFMA16(a, b, c) __builtin_amdgcn_mfma_f32_16x16x32_bf16(a, b, c, 0, 0, 0)

// ---------------------------------------------------------------------------
// Main: 128 blocks x 512 threads. PA frags resident in regs.
// Per step: [top prefetch] A:pa  B:W1  C:W2 + pc-GEMM + old-snap
//           D:W3 + NE -> valsT/outp + lane-local pc fixup -> Xs.
// 4 lgkm-only barriers/step. All epilogues lane (q,l15) owns (row q, n0/n1).
// ---------------------------------------------------------------------------
__global__ __launch_bounds__(512) void
scm_main(const float* __restrict__ emb, const float* __restrict__ pab,
         const float* __restrict__ mb1, const float* __restrict__ mb2,
         const float* __restrict__ mb3, const unsigned short* __restrict__ adjb,
         const __bf16* __restrict__ wsbf, float* __restrict__ outp) {
    __shared__ unsigned short valsT[1024 * VSTR];  // [col=b*256+d][var] 80 KB
    __shared__ unsigned short Xs[4 * XSTR];
    __shared__ unsigned short X2[4 * XSTR];
    __shared__ unsigned short Hs1[4 * HSTR];
    __shared__ unsigned short Hs2[4 * HSTR];

    const int tid = threadIdx.x, blk = blockIdx.x;

    {   // zero valsT (1024*40 ushorts = 5120 uint4)
        uint4 z; z.x = z.y = z.z = z.w = 0;
        for (int k = tid; k < 5120; k += 512) ((uint4*)valsT)[k] = z;
    }

    const int wid = tid >> 6, lane = tid & 63, l15 = lane & 15, q = lane >> 4;
    const int l3 = l15 & 3;                 // A-frag row (BTILE=4; rows alias)
    const int nW = wid * 16 + l15;
    const int n0 = nW, n1 = nW + 128;

    const float pb0 = pab[n0], pb1 = pab[n1];

    // ---- PA fragments: load ONCE, resident in 64 VGPRs for all 96 steps ----
    bf16x8 paf0[8], paf1[8];
    #pragma unroll
    for (int ks = 0; ks < 8; ks++) {
        paf0[ks] = *(const bf16x8*)(wsbf + ELOFF_PA + ((wid * 8 + ks) * 64 + lane) * 8);
        paf1[ks] = *(const bf16x8*)(wsbf + ELOFF_PA + (((wid + 8) * 8 + ks) * 64 + lane) * 8);
    }

    // seed Xs for step 0: vals = 0 -> pc = 0 -> X = emb_0 (ownership (q,n0/n1))
    Xs[q * XSTR + n0] = f2b(emb[n0]);
    Xs[q * XSTR + n1] = f2b(emb[n1]);
    bar_lds();

    for (int s = 0; s < 3 * N_VARS; s++) {
        const int i = s & 31, ni = (s + 1) & 31;
        const bool last = s >= 64;

        // ---- step-top prefetch: all per-var step-i globals ----
        float bi1 = mb1[i * 128 + nW];
        float bi2 = mb2[i * 128 + nW];
        float b3a = mb3[i * 256 + n0];
        float b3b = mb3[i * 256 + n1];
        bf16x8 w1f[8];
        #pragma unroll
        for (int ks = 0; ks < 8; ks++)
            w1f[ks] = *(const bf16x8*)(wsbf + ELOFF_W1 + (size_t)i * 32768 +
                                       ((wid * 8 + ks) * 64 + lane) * 8);
        bf16x8 w2f[4], w3f0[4], w3f1[4];
        #pragma unroll
        for (int ks = 0; ks < 4; ks++) {
            w2f[ks]  = *(const bf16x8*)(wsbf + ELOFF_W2 + (size_t)i * 16384 +
                                        ((wid * 4 + ks) * 64 + lane) * 8);
            w3f0[ks] = *(const bf16x8*)(wsbf + ELOFF_W3 + (size_t)i * 32768 +
                                        ((wid * 4 + ks) * 64 + lane) * 8);
            w3f1[ks] = *(const bf16x8*)(wsbf + ELOFF_W3 + (size_t)i * 32768 +
                                        (((wid + 8) * 4 + ks) * 64 + lane) * 8);
        }
        // NE contribution (row q, cols n0/n1)
        const size_t obq = ((size_t)(blk * BTILE + q) * 32 + i) * 256;
        const float neq0 = outp[obq + n0];
        const float neq1 = outp[obq + n1];
        // adjacency A-frags (hi/lo) for next-var pc GEMM + scalar an[i], emb(ni)
        bf16x8 anh = *(const bf16x8*)(adjb + ni * 64 + q * 8);
        bf16x8 anl = *(const bf16x8*)(adjb + ni * 64 + 32 + q * 8);
        const float ani = b2f(adjb[ni * 64 + i]) + b2f(adjb[ni * 64 + 32 + i]);
        const float e0 = emb[ni * 256 + n0];
        const float e1 = emb[ni * 256 + n1];

        // ==== A: pa = gelu(X @ pa_W + pa_b) ====  (regs + LDS only)
        {
            f32x4 a0e = {0, 0, 0, 0}, a0o = {0, 0, 0, 0};
            f32x4 a1e = {0, 0, 0, 0}, a1o = {0, 0, 0, 0};
            #pragma unroll
            for (int ks = 0; ks < 8; ks += 2) {
                bf16x8 af0 = *(const bf16x8*)(Xs + l3 * XSTR + ks * 32 + q * 8);
                bf16x8 af1 = *(const bf16x8*)(Xs + l3 * XSTR + (ks + 1) * 32 + q * 8);
                a0e = MFMA16(af0, paf0[ks], a0e);
                a1e = MFMA16(af0, paf1[ks], a1e);
                a0o = MFMA16(af1, paf0[ks + 1], a0o);
                a1o = MFMA16(af1, paf1[ks + 1], a1o);
            }
            float s0 = pickq(a0e, q) + pickq(a0o, q) + pb0;
            float s1 = pickq(a1e, q) + pickq(a1o, q) + pb1;
            X2[q * XSTR + n0] = f2b(gelu_e(s0));
            X2[q * XSTR + n1] = f2b(gelu_e(s1));
        }
        bar_lds();

        // ==== B: W1 GEMM ====
        {
            f32x4 aa = {0, 0, 0, 0}, ab = {0, 0, 0, 0};
            f32x4 ac = {0, 0, 0, 0}, ad = {0, 0, 0, 0};
            #pragma unroll
            for (int ks = 0; ks < 8; ks += 4) {
                bf16x8 af0 = *(const bf16x8*)(X2 + l3 * XSTR + ks * 32 + q * 8);
                bf16x8 af1 = *(const bf16x8*)(X2 + l3 * XSTR + (ks + 1) * 32 + q * 8);
                bf16x8 af2 = *(const bf16x8*)(X2 + l3 * XSTR + (ks + 2) * 32 + q * 8);
                bf16x8 af3 = *(const bf16x8*)(X2 + l3 * XSTR + (ks + 3) * 32 + q * 8);
                aa = MFMA16(af0, w1f[ks], aa);
                ab = MFMA16(af1, w1f[ks + 1], ab);
                ac = MFMA16(af2, w1f[ks + 2], ac);
                ad = MFMA16(af3, w1f[ks + 3], ad);
            }
            float sb = (pickq(aa, q) + pickq(ab, q)) +
                       (pickq(ac, q) + pickq(ad, q)) + bi1;
            Hs1[q * HSTR + nW] = f2b(gelu_e(sb));
        }
        bar_lds();

        // ==== C: W2 GEMM; pc GEMM (pre-update valsT, hi/lo an); old_i snap ====
        f32x4 P0[4], P1[4];
        float o0, o1;
        {
            f32x4 ca = {0, 0, 0, 0}, cb = {0, 0, 0, 0};
            #pragma unroll
            for (int ks = 0; ks < 4; ks += 2) {
                bf16x8 af0 = *(const bf16x8*)(Hs1 + l3 * HSTR + ks * 32 + q * 8);
                bf16x8 af1 = *(const bf16x8*)(Hs1 + l3 * HSTR + (ks + 1) * 32 + q * 8);
                ca = MFMA16(af0, w2f[ks], ca);
                cb = MFMA16(af1, w2f[ks + 1], cb);
            }
            // pc: one K=32 tile per (b=t, col set). B-frag = 8 contiguous vars.
            #pragma unroll
            for (int t = 0; t < 4; t++) {
                bf16x8 vf0 = *(const bf16x8*)(valsT + (t * 256 + n0) * VSTR + q * 8);
                bf16x8 vf1 = *(const bf16x8*)(valsT + (t * 256 + n1) * VSTR + q * 8);
                f32x4 z = {0, 0, 0, 0};
                P0[t] = MFMA16(anl, vf0, MFMA16(anh, vf0, z));
                P1[t] = MFMA16(anl, vf1, MFMA16(anh, vf1, z));
            }
            o0 = b2f(valsT[(q * 256 + n0) * VSTR + i]);
            o1 = b2f(valsT[(q * 256 + n1) * VSTR + i]);
            float scv = pickq(ca, q) + pickq(cb, q) + bi2;
            Hs2[q * HSTR + nW] = f2b(gelu_e(scv));
        }
        bar_lds();

        // ==== D: W3 + b3 + NE -> valsT/outp; lane-local pc fixup -> Xs ====
        {
            f32x4 c0a = {0, 0, 0, 0}, c0b = {0, 0, 0, 0};
            f32x4 c1a = {0, 0, 0, 0}, c1b = {0, 0, 0, 0};
            #pragma unroll
            for (int ks = 0; ks < 4; ks += 2) {
                bf16x8 af0 = *(const bf16x8*)(Hs2 + l3 * HSTR + ks * 32 + q * 8);
                bf16x8 af1 = *(const bf16x8*)(Hs2 + l3 * HSTR + (ks + 1) * 32 + q * 8);
                c0a = MFMA16(af0, w3f0[ks], c0a);
                c1a = MFMA16(af0, w3f1[ks], c1a);
                c0b = MFMA16(af1, w3f0[ks + 1], c0b);
                c1b = MFMA16(af1, w3f1[ks + 1], c1b);
            }
            float v0 = pickq(c0a, q) + pickq(c0b, q) + b3a + neq0;
            float v1 = pickq(c1a, q) + pickq(c1b, q) + b3b + neq1;
            unsigned short ur0 = f2b(v0), ur1 = f2b(v1);
            valsT[(q * 256 + n0) * VSTR + i] = ur0;
            valsT[(q * 256 + n1) * VSTR + i] = ur1;
            if (last) {
                outp[obq + n0] = v0;
                outp[obq + n1] = v1;
            }
            // pc fixup: pc_pre + an[i]*(bf16(new)-bf16(old)) + emb -> Xs(ni)
            float pc0 = pick4(P0[0][0], P0[1][0], P0[2][0], P0[3][0], q);
            float pc1 = pick4(P1[0][0], P1[1][0], P1[2][0], P1[3][0], q);
            float x0 = pc0 + ani * (b2f(ur0) - o0) + e0;
            float x1 = pc1 + ani * (b2f(ur1) - o1) + e1;
            Xs[q * XSTR + n0] = f2b(x0);
            Xs[q * XSTR + n1] = f2b(x1);
        }
        bar_lds();
    }
}

extern "C" void kernel_launch(void* const* d_in, const int* in_sizes, int n_in,
                              void* d_out, int out_size, void* d_ws, size_t ws_size,
                              hipStream_t stream) {
    (void)in_sizes; (void)n_in; (void)out_size; (void)ws_size;
    const float* noise = (const float*)d_in[0];
    const float* edge  = (const float*)d_in[1];
    const float* emb   = (const float*)d_in[2];
    const float* paW   = (const float*)d_in[3];
    const float* pab   = (const float*)d_in[4];
    const float* mW1   = (const float*)d_in[5];
    const float* mb1   = (const float*)d_in[6];
    const float* mW2   = (const float*)d_in[7];
    const float* mb2   = (const float*)d_in[8];
    const float* mW3   = (const float*)d_in[9];
    const float* mb3   = (const float*)d_in[10];
    const float* neW   = (const float*)d_in[11];
    const float* neb   = (const float*)d_in[12];
    float* outp = (float*)d_out;

    unsigned short* adjb = (unsigned short*)d_ws;             // 4 KB: hi/lo adj
    unsigned short* wsb  = (unsigned short*)((char*)d_ws + 4096);

    prep_all<<<1545, 256, 0, stream>>>(paW, mW1, mW2, mW3, edge, wsb, adjb,
                                       noise, neW, neb, outp);
    scm_main<<<NBLK, 512, 0, stream>>>(emb, pab, mb1, mb2, mb3, adjb,
                                       (const __bf16*)wsb, outp);
}